// Round 12
// baseline (202.396 us; speedup 1.0000x reference)
//
#include <hip/hip_runtime.h>
#include <math.h>

#define D_    100
#define DM_   200
#define DI_   400
#define G4_   1600
#define NN_   200
#define KP_   224   // padded K for MFMA (200 -> 224 = 7*32)

typedef __attribute__((ext_vector_type(8))) short bf16x8;
typedef __attribute__((ext_vector_type(4))) float f32x4;

__device__ __forceinline__ float sigf(float x){ return 1.0f/(1.0f+__expf(-x)); }
__device__ __forceinline__ unsigned short f2bf(float f){
    unsigned int b = __float_as_uint(f);
    b = (b + 0x7fffu + ((b>>16)&1u)) >> 16;
    return (unsigned short)b;
}
__device__ __forceinline__ float bf_lo(unsigned int w){ return __uint_as_float(w<<16); }
__device__ __forceinline__ float bf_hi(unsigned int w){ return __uint_as_float(w & 0xffff0000u); }

// ---------------------------------------------------------------------------
// warm1: stream float4 ranges into L2 with per-XCD coverage (r9 proven).
__global__ __launch_bounds__(256) void warm_kernel(
    const float4* __restrict__ p0, int n0, const float4* __restrict__ p1, int n1,
    const float4* __restrict__ p2, int n2, const float4* __restrict__ p3, int n3,
    const float4* __restrict__ p4, int n4, float* __restrict__ dump)
{
    int tid = threadIdx.x, bid = blockIdx.x;
    int total = n0 + n1 + n2 + n3 + n4;
    int nsl = gridDim.x >> 3;
    int slice = bid >> 3;
    int chunk = (total + nsl - 1) / nsl;
    int start = slice * chunk;
    int end = min(start + chunk, total);
    float acc = 0.f;
    for (int i = start + tid; i < end; i += 256){
        int j = i; const float4* p;
        if (j < n0) p = p0;
        else { j -= n0;
            if (j < n1) p = p1;
            else { j -= n1;
                if (j < n2) p = p2;
                else { j -= n2;
                    if (j < n3) p = p3;
                    else { j -= n3; p = p4; } } } }
        float4 v = p[j];
        acc += v.x + v.y + v.z + v.w;
    }
    #pragma unroll
    for (int o = 32; o; o >>= 1) acc += __shfl_down(acc, o);
    if ((tid & 63) == 0) dump[bid*4 + (tid >> 6)] = acc;
}

// ---------------------------------------------------------------------------
// prep: merged wtrans (blocks 0..349) + warm Whh[200:] (350..861) +
//       warm seW1/seW2 (862..1373).  256 thr.
__global__ __launch_bounds__(256) void prep_kernel(
    const float* __restrict__ Wih, const float* __restrict__ Whh,
    const float* __restrict__ seW1, const float* __restrict__ seW2,
    unsigned short* __restrict__ Bt0, unsigned short* __restrict__ Bt1,
    float* __restrict__ dump)
{
    int b = blockIdx.x, tid = threadIdx.x;
    if (b < 350){
        int m = b / 175; int bb = b - m*175;
        int kt = bb / 25, ct = bb % 25;
        const float* W = m ? Whh : Wih;
        unsigned short* Bt = m ? Bt1 : Bt0;
        int k0 = kt*32, c0 = ct*64;
        __shared__ float t[32][65];
        for (int idx = tid; idx < 2048; idx += 256){
            int kk = idx >> 6, c = idx & 63;
            int k = k0 + kk;
            t[kk][c] = (k < 200) ? W[(long)k*G4_ + c0 + c] : 0.f;
        }
        __syncthreads();
        for (int idx = tid; idx < 1024; idx += 256){
            int c = idx >> 4, p = idx & 15;
            unsigned int u0 = f2bf(t[p*2][c]);
            unsigned int u1 = f2bf(t[p*2+1][c]);
            *(unsigned int*)(Bt + (long)(c0+c)*KP_ + k0 + p*2) = u0 | (u1 << 16);
        }
        return;
    }
    // warm sections: 512 blocks each, 8-block XCD slices
    const float4* p; int total; int sub;
    if (b < 862){ sub = b - 350; p = (const float4*)(Whh + 200*G4_); total = 80000; }
    else        { sub = b - 862; p = (const float4*)seW1;            total = 40000; } // seW1(20000)+seW2(20000) contiguous? no -> handle below
    int nsl = 64, slice = sub >> 3;
    int chunk = (total + nsl - 1) / nsl;
    int start = slice * chunk;
    int end = min(start + chunk, total);
    float acc = 0.f;
    if (b < 862){
        for (int i = start + tid; i < end; i += 256){ float4 v = p[i]; acc += v.x+v.y+v.z+v.w; }
    } else {
        const float4* q1 = (const float4*)seW1;
        const float4* q2 = (const float4*)seW2;
        for (int i = start + tid; i < end; i += 256){
            float4 v = (i < 20000) ? q1[i] : q2[i-20000];
            acc += v.x+v.y+v.z+v.w;
        }
    }
    #pragma unroll
    for (int o = 32; o; o >>= 1) acc += __shfl_down(acc, o);
    if ((tid & 63) == 0) dump[b*4 + (tid >> 6)] = acc;
}

// ---------------------------------------------------------------------------
// Kernel 1: views v7 (r10/r11 proven).  grid = 1250, 128 thr, 8 rows/block.
__global__ __launch_bounds__(128) void views_kernel(
    const float* __restrict__ ent_emb, const float* __restrict__ rel_emb,
    const float* __restrict__ W1, const float* __restrict__ b1,
    const float* __restrict__ W2, const float* __restrict__ b2,
    const float* __restrict__ W3, const float* __restrict__ b3,
    const float* __restrict__ attW1, const float* __restrict__ attW2,
    unsigned short* __restrict__ ent_bf, float* __restrict__ rs_in, float* __restrict__ rs_out)
{
    int bid = blockIdx.x, tid = threadIdx.x;
    bool isRel = bid < 625;
    int row0 = (isRel ? bid : bid - 625) * 8;
    const float* src = isRel ? rel_emb : ent_emb;

    __shared__ float4 eT4[25][9];
    __shared__ float  ys[3][8][D_];
    __shared__ float  invn[3][8];
    __shared__ float  aws[2][D_];

    for (int idx = tid; idx < 200; idx += 128){
        int r = idx / 25, c4 = idx % 25;
        eT4[c4][r] = *(const float4*)(src + (long)(row0+r)*D_ + c4*4);
    }
    if (isRel){
        for (int idx = tid; idx < 200; idx += 128)
            aws[idx/100][idx%100] = (idx < 100) ? attW1[idx] : attW2[idx-100];
    }
    __syncthreads();

    if (tid < 75){
        int v = tid / 25, cq = tid % 25, c0 = cq*4;
        const float* Wv = (v==0) ? W1 : (v==1) ? W2 : W3;
        const float* bv = (v==0) ? b1 : (v==1) ? b2 : b3;
        float4 bb = *(const float4*)(bv + c0);
        float acc[8][4];
        #pragma unroll
        for (int r = 0; r < 8; ++r){
            acc[r][0]=bb.x; acc[r][1]=bb.y; acc[r][2]=bb.z; acc[r][3]=bb.w;
        }
        for (int k4 = 0; k4 < 25; ++k4){
            const float* Wk = Wv + (long)(k4*4)*D_ + c0;
            float4 w0 = *(const float4*)(Wk);
            float4 w1 = *(const float4*)(Wk + D_);
            float4 w2 = *(const float4*)(Wk + 2*D_);
            float4 w3 = *(const float4*)(Wk + 3*D_);
            #pragma unroll
            for (int r = 0; r < 8; ++r){
                float4 e = eT4[k4][r];
                acc[r][0] += e.x*w0.x + e.y*w1.x + e.z*w2.x + e.w*w3.x;
                acc[r][1] += e.x*w0.y + e.y*w1.y + e.z*w2.y + e.w*w3.y;
                acc[r][2] += e.x*w0.z + e.y*w1.z + e.z*w2.z + e.w*w3.z;
                acc[r][3] += e.x*w0.w + e.y*w1.w + e.z*w2.w + e.w*w3.w;
            }
        }
        #pragma unroll
        for (int r = 0; r < 8; ++r)
            *(float4*)(&ys[v][r][c0]) = make_float4(acc[r][0], acc[r][1], acc[r][2], acc[r][3]);
    }
    __syncthreads();

    if (tid < 24){
        int v = tid / 8, r = tid % 8;
        float s = 0.f;
        #pragma unroll 4
        for (int j = 0; j < D_; ++j){ float t = ys[v][r][j]; s += t*t; }
        invn[v][r] = 1.f / fmaxf(sqrtf(s), 1e-12f);
    }
    __syncthreads();

    if (isRel){
        if (tid < 48){
            int which = tid & 1, p = tid >> 1;
            int v = p / 8, r = p % 8;
            float s = 0.f;
            #pragma unroll 4
            for (int j = 0; j < D_; ++j) s += ys[v][r][j]*aws[which][j];
            (which ? rs_out : rs_in)[(row0+r)*3+v] = s * invn[v][r];
        }
    } else {
        for (int idx = tid; idx < 600; idx += 128){
            int v = idx / 200, rq = idx - v*200;
            int r = rq / 25, c0 = (rq % 25)*4;
            float inv = invn[v][r];
            float4 y4 = *(const float4*)(&ys[v][r][c0]);
            ushort4 o;
            o.x = f2bf(y4.x*inv); o.y = f2bf(y4.y*inv);
            o.z = f2bf(y4.z*inv); o.w = f2bf(y4.w*inv);
            *(ushort4*)(ent_bf + ((long)(row0+r)*3+v)*D_ + c0) = o;
        }
    }
}

// ---------------------------------------------------------------------------
// Kernel 2: neigh (proven tree-softmax).  grid = (518, 3), 512 thr.
__global__ __launch_bounds__(512) void neigh_kernel(
    const int* __restrict__ qlc_out, const int* __restrict__ qlc_in,
    const int* __restrict__ qrc_out, const int* __restrict__ qrc_in,
    const int* __restrict__ slc_out, const int* __restrict__ slc_in,
    const int* __restrict__ src_out, const int* __restrict__ src_in,
    const unsigned short* __restrict__ ent_bf, const float* __restrict__ rs_in,
    const float* __restrict__ rs_out,
    float* __restrict__ X)
{
    int u = blockIdx.x, v = blockIdx.y, tid = threadIdx.x;
    const int *cin, *cout; int row, colOff;
    if      (u < 256){ int n=u;     cout=qlc_out+n*NN_*2; cin=qlc_in+n*NN_*2; row=v*256+n;   colOff=0;   }
    else if (u < 512){ int n=u-256; cout=qrc_out+n*NN_*2; cin=qrc_in+n*NN_*2; row=v*256+n;   colOff=100; }
    else if (u < 515){ int f=u-512; cout=slc_out+f*NN_*2; cin=slc_in+f*NN_*2; row=768+f*3+v; colOff=0;   }
    else             { int f=u-515; cout=src_out+f*NN_*2; cin=src_in+f*NN_*2; row=768+f*3+v; colOff=100; }

    __shared__ int   ioff[NN_], ooff[NN_];
    __shared__ float ain[NN_], aout[NN_];
    __shared__ float sv[2][NN_];
    __shared__ float red[512];
    __shared__ float pin[4][D_], pout[4][D_];

    if (tid < NN_){
        int rrel = cin[tid*2], rent = cin[tid*2+1];
        ioff[tid] = (rent*3+v)*D_;
        sv[0][tid] = rs_in[rrel*3+v];
    } else if (tid >= 256 && tid < 256+NN_){
        int k = tid - 256;
        int rrel = cout[k*2], rent = cout[k*2+1];
        ooff[k] = (rent*3+v)*D_;
        sv[1][k] = rs_out[rrel*3+v];
    }
    __syncthreads();

    int half = tid >> 8, l = tid & 255, base = half << 8;
    float x = (l < NN_) ? sv[half][l] : -1e30f;
    red[tid] = x; __syncthreads();
    for (int s = 128; s > 0; s >>= 1){
        if (l < s) red[base+l] = fmaxf(red[base+l], red[base+l+s]);
        __syncthreads();
    }
    float m = red[base]; __syncthreads();
    float e = (l < NN_) ? __expf(x - m) : 0.f;
    red[tid] = e; __syncthreads();
    for (int s = 128; s > 0; s >>= 1){
        if (l < s) red[base+l] += red[base+l+s];
        __syncthreads();
    }
    float S = red[base];
    if (l < NN_){ if (half) aout[l] = e/S; else ain[l] = e/S; }
    __syncthreads();

    int g = tid >> 6, ln = tid & 63;
    if (ln < 50){
        int d0 = ln*2;
        bool isOut = g >= 4;
        int k0 = (g & 3) * 50;
        const int*   offA = isOut ? ooff : ioff;
        const float* aA   = isOut ? aout : ain;
        float acc0 = 0.f, acc1 = 0.f;
        #pragma unroll 5
        for (int kk = 0; kk < 50; ++kk){
            int k = k0 + kk;
            unsigned int w = *(const unsigned int*)(ent_bf + offA[k] + d0);
            float a = aA[k];
            acc0 += a * bf_lo(w);
            acc1 += a * bf_hi(w);
        }
        float2* p = isOut ? (float2*)&pout[g&3][d0] : (float2*)&pin[g&3][d0];
        *p = make_float2(acc0, acc1);
    }
    __syncthreads();

    if (tid < D_){
        float hi = pin[0][tid]+pin[1][tid]+pin[2][tid]+pin[3][tid];
        float ho = pout[0][tid]+pout[1][tid]+pout[2][tid]+pout[3][tid];
        float ea = __expf(hi), ec = __expf(ho);
        X[(long)row*DM_ + colOff + tid] = tanhf((hi*ea + ho*ec)/(ea+ec));
    }
}

// ---------------------------------------------------------------------------
// Kernel 3: senc v8 fused (r10/r11 proven) + fused Abf bf16 store.
// grid = 389, 512 thr, 2 rows/block.
__global__ __launch_bounds__(512) void senc_kernel(
    const float* __restrict__ X,
    const float* __restrict__ seW1, const float* __restrict__ seb1,
    const float* __restrict__ seW2, const float* __restrict__ seb2,
    const float* __restrict__ ln_g, const float* __restrict__ ln_b,
    float* __restrict__ qg, float* __restrict__ sEnc,
    unsigned short* __restrict__ Abf)
{
    int b = blockIdx.x, tid = threadIdx.x;
    int r0 = b*2;

    __shared__ float xT[DM_][2];
    __shared__ float tT[DI_][2];
    __shared__ float pc[2][DM_][2];
    __shared__ float hv[2][DM_];
    __shared__ float part[2][4][2];

    for (int idx = tid; idx < 400; idx += 512){
        int r = idx / DM_, k = idx - r*DM_;
        int row = r0 + r;
        xT[k][r] = (row < 777) ? X[(long)row*DM_ + k] : 0.f;
    }
    __syncthreads();

    if (tid < DI_){
        int col = tid;
        float a0, a1; a0 = a1 = seb1[col];
        #pragma unroll 4
        for (int k = 0; k < DM_; ++k){
            float w = seW1[(long)k*DI_ + col];
            float2 e = *(const float2*)(&xT[k][0]);
            a0 += e.x*w; a1 += e.y*w;
        }
        tT[col][0] = fmaxf(a0, 0.f);
        tT[col][1] = fmaxf(a1, 0.f);
    }
    __syncthreads();

    if (tid < 400){
        int col = tid % DM_, kh = tid / DM_;
        float a0 = 0.f, a1 = 0.f;
        #pragma unroll 4
        for (int kk = 0; kk < 200; ++kk){
            int k = kh*200 + kk;
            float w = seW2[(long)k*DM_ + col];
            float2 t = *(const float2*)(&tT[k][0]);
            a0 += t.x*w; a1 += t.y*w;
        }
        pc[kh][col][0] = a0; pc[kh][col][1] = a1;
    }
    __syncthreads();

    if (tid < DM_){
        int col = tid;
        float bb = seb2[col];
        hv[0][col] = pc[0][col][0] + pc[1][col][0] + bb + xT[col][0];
        hv[1][col] = pc[0][col][1] + pc[1][col][1] + bb + xT[col][1];
    }
    __syncthreads();

    {
        int row = tid >> 8, l = tid & 255, w = l >> 6, lane = l & 63;
        float v = (l < DM_) ? hv[row][l] : 0.f;
        float s1 = v, s2 = v*v;
        #pragma unroll
        for (int o = 32; o; o >>= 1){ s1 += __shfl_down(s1, o); s2 += __shfl_down(s2, o); }
        if (lane == 0){ part[row][w][0] = s1; part[row][w][1] = s2; }
    }
    __syncthreads();

    if (tid < 400){
        int row = tid / DM_, col = tid % DM_;
        int grow = r0 + row;
        if (grow < 777){
            float s1 = part[row][0][0]+part[row][1][0]+part[row][2][0]+part[row][3][0];
            float s2 = part[row][0][1]+part[row][1][1]+part[row][2][1]+part[row][3][1];
            float mu = s1 * (1.f/DM_);
            float rs = rsqrtf(s2 * (1.f/DM_) - mu*mu + 1e-5f);
            float val = ln_g[col]*(hv[row][col]-mu)*rs + ln_b[col];
            if (grow < 768){
                qg[(long)grow*DM_ + col] = val;
                Abf[(long)grow*KP_ + col] = f2bf(val);
            } else {
                sEnc[(long)(grow-768)*DM_ + col] = val;
            }
        }
    } else if (tid < 448){
        int t = tid - 400;
        int rr = t / 24, cc = t % 24;
        int grow = r0 + rr;
        if (grow < 768) Abf[(long)grow*KP_ + 200 + cc] = 0;
    }
}

// ---------------------------------------------------------------------------
// Kernel 4: sw (+ sg).  grid = 75, 64 thr.
__global__ __launch_bounds__(64) void sw_kernel(
    const float* __restrict__ sEnc, const float* __restrict__ Whh,
    float* __restrict__ sg, float* __restrict__ sW)
{
    int b = blockIdx.x, tid = threadIdx.x;
    int s = b / 25, c0 = (b - s*25)*64;
    __shared__ float sgl[DM_];
    for (int j = tid; j < DM_; j += 64){
        float val = (sEnc[s*DM_ + j] + sEnc[(3+s)*DM_ + j] + sEnc[(6+s)*DM_ + j]) * (1.f/3.f);
        sgl[j] = val;
        if (c0 == 0) sg[s*DM_ + j] = val;
    }
    __syncthreads();
    int col = c0 + tid;
    float acc = 0.f;
    #pragma unroll 4
    for (int i = 0; i < DM_; ++i) acc += sgl[i] * Whh[(long)(DM_+i)*G4_ + col];
    sW[s*G4_ + col] = acc;
}

// ---------------------------------------------------------------------------
// lstm megakernel: entire 4-step scan. grid = 48 blocks x 256 thr (16 rows/blk).
// Per step: 4-quadrant MFMA (gates in registers) -> cell math -> h/c/alpha in LDS.
__global__ __launch_bounds__(256) void lstm_kernel(
    const unsigned short* __restrict__ Abf,
    const unsigned short* __restrict__ Bt0, const unsigned short* __restrict__ Bt1,
    const float* __restrict__ qg, const float* __restrict__ sg,
    const float* __restrict__ sW, const float* __restrict__ bih,
    const float* __restrict__ bhh,
    float* __restrict__ qW0, float* __restrict__ sAll)
{
    int b = blockIdx.x, tid = threadIdx.x;
    int row0 = b*16;
    int lane = tid & 63, w = tid >> 6;
    int cr = lane & 15;
    int kg = (lane >> 4) * 8;

    __shared__ unsigned short A_lds[16][232];   // h in bf16 (pad stride: 2-way banks)
    __shared__ float cst[16][404];
    __shared__ float hbuf[16][204];
    __shared__ float qgl[16][200];
    __shared__ float sup[600];
    __shared__ float alf[16][3];
    __shared__ float lg[16][3];

    for (int idx = tid; idx < 448; idx += 256){
        int r = idx / 28, c = idx % 28;
        *(uint4*)(&A_lds[r][c*8]) = *(const uint4*)(Abf + (long)(row0+r)*KP_ + c*8);
    }
    for (int idx = tid; idx < 800; idx += 256){
        int r = idx / 50, c = idx % 50;
        *(float4*)(&qgl[r][c*4]) = *(const float4*)(qg + (long)(row0+r)*DM_ + c*4);
    }
    for (int idx = tid; idx < 600; idx += 256) sup[idx] = sg[idx];
    for (int idx = tid; idx < 16*404; idx += 256) (&cst[0][0])[idx] = 0.f;
    __syncthreads();

    for (int step = 0; step < 4; ++step){
        const unsigned short* Bt = step ? Bt1 : Bt0;
        bf16x8 a[7];
        #pragma unroll
        for (int kt = 0; kt < 7; ++kt)
            a[kt] = *(const bf16x8*)(&A_lds[cr][kg + kt*32]);
        __syncthreads();                 // all A reads done before epilogue writes

        for (int tj = w; tj < 25; tj += 4){
            int jc = tj*16 + cr;         // logical col 0..399
            const unsigned short* BI = Bt + (long)(jc       )*KP_ + kg;
            const unsigned short* BF = Bt + (long)(jc +  400)*KP_ + kg;
            const unsigned short* BG = Bt + (long)(jc +  800)*KP_ + kg;
            const unsigned short* BO = Bt + (long)(jc + 1200)*KP_ + kg;
            f32x4 ai = {0,0,0,0}, af = {0,0,0,0}, ag = {0,0,0,0}, ao = {0,0,0,0};
            #pragma unroll
            for (int kt = 0; kt < 7; ++kt){
                ai = __builtin_amdgcn_mfma_f32_16x16x32_bf16(a[kt], *(const bf16x8*)(BI + kt*32), ai, 0, 0, 0);
                af = __builtin_amdgcn_mfma_f32_16x16x32_bf16(a[kt], *(const bf16x8*)(BF + kt*32), af, 0, 0, 0);
                ag = __builtin_amdgcn_mfma_f32_16x16x32_bf16(a[kt], *(const bf16x8*)(BG + kt*32), ag, 0, 0, 0);
                ao = __builtin_amdgcn_mfma_f32_16x16x32_bf16(a[kt], *(const bf16x8*)(BO + kt*32), ao, 0, 0, 0);
            }
            float addI = 0.f, addF = 0.f, addG = 0.f, addO = 0.f;
            if (step == 0){
                addI = bih[jc]      + bhh[jc];
                addF = bih[400+jc]  + bhh[400+jc];
                addG = bih[800+jc]  + bhh[800+jc];
                addO = bih[1200+jc] + bhh[1200+jc];
            }
            #pragma unroll
            for (int i = 0; i < 4; ++i){
                int rl = (lane >> 4)*4 + i;
                int grow = row0 + rl;
                float gi, gf, gg, go;
                if (step == 0){
                    gi = ai[i] + addI; gf = af[i] + addF;
                    gg = ag[i] + addG; go = ao[i] + addO;
                    float* qp = qW0 + (long)grow*G4_;
                    qp[jc] = gi; qp[400+jc] = gf; qp[800+jc] = gg; qp[1200+jc] = go;
                } else {
                    float A0 = alf[rl][0], A1 = alf[rl][1], A2 = alf[rl][2];
                    const float* qp = qW0 + (long)grow*G4_;
                    gi = ai[i] + qp[jc]       + A0*sW[jc]        + A1*sW[1600+jc]      + A2*sW[3200+jc];
                    gf = af[i] + qp[400+jc]   + A0*sW[400+jc]    + A1*sW[2000+jc]      + A2*sW[3600+jc];
                    gg = ag[i] + qp[800+jc]   + A0*sW[800+jc]    + A1*sW[2400+jc]      + A2*sW[4000+jc];
                    go = ao[i] + qp[1200+jc]  + A0*sW[1200+jc]   + A1*sW[2800+jc]      + A2*sW[4400+jc];
                }
                float cold = cst[rl][jc];
                float c2 = sigf(gf)*cold + sigf(gi)*tanhf(gg);
                cst[rl][jc] = c2;
                float h2 = sigf(go)*tanhf(c2);
                if (jc < DM_){
                    float hval = qgl[rl][jc] + h2;
                    hbuf[rl][jc] = hval;
                    A_lds[rl][jc] = f2bf(hval);
                }
            }
        }
        __syncthreads();                 // hbuf/cst/A_lds complete

        if (step < 3){
            int r = tid >> 4, l = tid & 15;
            #pragma unroll
            for (int s = 0; s < 3; ++s){
                float part = 0.f;
                for (int d = l; d < DM_; d += 16) part += hbuf[r][d]*sup[s*DM_+d];
                #pragma unroll
                for (int o = 8; o; o >>= 1) part += __shfl_down(part, o, 16);
                if (!l) lg[r][s] = part;
            }
            __syncthreads();
            if (tid < 16){
                float l0 = lg[tid][0], l1 = lg[tid][1], l2 = lg[tid][2];
                float m = fmaxf(l0, fmaxf(l1, l2));
                float e0 = __expf(l0-m), e1 = __expf(l1-m), e2 = __expf(l2-m);
                float inv = 1.f/(e0+e1+e2);
                alf[tid][0] = e0*inv; alf[tid][1] = e1*inv; alf[tid][2] = e2*inv;
            }
            __syncthreads();
        } else {
            int v = b >> 4;
            int r = tid >> 4, l = tid & 15;
            float part = 0.f;
            for (int d = l; d < DM_; d += 16) part += hbuf[r][d]*sup[v*DM_+d];
            #pragma unroll
            for (int o = 8; o; o >>= 1) part += __shfl_down(part, o, 16);
            if (!l) sAll[row0+r] = part;
        }
    }
}

// ---------------------------------------------------------------------------
__global__ void final_kernel(const float* __restrict__ sAll, float* __restrict__ out){
    int n = blockIdx.x*blockDim.x + threadIdx.x;
    if (n < 256) out[n] = fmaxf(sAll[n], fmaxf(sAll[256+n], sAll[512+n]));
}

// ---------------------------------------------------------------------------
extern "C" void kernel_launch(void* const* d_in, const int* in_sizes, int n_in,
                              void* d_out, int out_size, void* d_ws, size_t ws_size,
                              hipStream_t stream)
{
    const float* ent_emb=(const float*)d_in[0];
    const float* rel_emb=(const float*)d_in[1];
    const float* W1=(const float*)d_in[2];  const float* b1=(const float*)d_in[3];
    const float* W2=(const float*)d_in[4];  const float* b2=(const float*)d_in[5];
    const float* W3=(const float*)d_in[6];  const float* b3=(const float*)d_in[7];
    const float* attW1=(const float*)d_in[8];
    const float* attW2=(const float*)d_in[10];
    const float* seW1=(const float*)d_in[12]; const float* seb1=(const float*)d_in[13];
    const float* seW2=(const float*)d_in[14]; const float* seb2=(const float*)d_in[15];
    const float* ln_g=(const float*)d_in[16]; const float* ln_b=(const float*)d_in[17];
    const float* Wih=(const float*)d_in[18];  const float* bih=(const float*)d_in[19];
    const float* Whh=(const float*)d_in[20];  const float* bhh=(const float*)d_in[21];
    const int* qlc_out=(const int*)d_in[24];  const int* qlc_in=(const int*)d_in[25];
    const int* qrc_out=(const int*)d_in[27];  const int* qrc_in=(const int*)d_in[28];
    const int* slc_out=(const int*)d_in[30];  const int* slc_in=(const int*)d_in[31];
    const int* src_out=(const int*)d_in[33];  const int* src_in=(const int*)d_in[34];

    float* ws = (float*)d_ws;
    unsigned short* ent_bf = (unsigned short*)ws;  // 1.5M bf16 (750k float slots)
    float* rs_in = ws + 1500000;       // 15,000
    float* rs_out= ws + 1515000;       // 15,000
    float* X     = ws + 1530000;       // 156,800 (784x200; neigh -> senc)
    float* qg    = ws + 1686800;       // 153,600
    float* sEnc  = ws + 1840400;       // 1,800
    float* sg    = ws + 1842200;       // 600
    float* qW0   = ws + 1842800;       // 1,228,800
    float* sW    = ws + 3381104;       // 4,800
    float* sAll  = ws + 3385904;       // 768
    float* dump  = ws + 3386672;       // 8,192 (warm sink)
    unsigned short* Abf = (unsigned short*)(ws + 3394864);  // 768x224 bf16
    unsigned short* Bt0 = (unsigned short*)(ws + 3480880);  // 1600x224 bf16
    unsigned short* Bt1 = (unsigned short*)(ws + 3660080);  // 1600x224 bf16

    // warm1: embeddings actually used (ent rows 0..4999, all rel) + W1-3
    warm_kernel<<<2048, 256, 0, stream>>>(
        (const float4*)ent_emb, 125000, (const float4*)rel_emb, 125000,
        (const float4*)W1, 2500, (const float4*)W2, 2500,
        (const float4*)W3, 2500, dump);
    views_kernel<<<1250, 128, 0, stream>>>(ent_emb, rel_emb, W1,b1,W2,b2,W3,b3,
                                           attW1, attW2, ent_bf, rs_in, rs_out);
    neigh_kernel<<<dim3(518,3), 512, 0, stream>>>(qlc_out,qlc_in,qrc_out,qrc_in,
                                                  slc_out,slc_in,src_out,src_in,
                                                  ent_bf, rs_in, rs_out, X);
    // prep: wtrans (Bt0/Bt1) + warm Whh[200:] + warm seW1/seW2
    prep_kernel<<<1374, 256, 0, stream>>>(Wih, Whh, seW1, seW2, Bt0, Bt1, dump);
    senc_kernel<<<389, 512, 0, stream>>>(X, seW1, seb1, seW2, seb2,
                                         ln_g, ln_b, qg, sEnc, Abf);
    sw_kernel<<<75, 64, 0, stream>>>(sEnc, Whh, sg, sW);
    lstm_kernel<<<48, 256, 0, stream>>>(Abf, Bt0, Bt1, qg, sg, sW, bih, bhh,
                                        qW0, sAll);
    final_kernel<<<1, 256, 0, stream>>>(sAll, (float*)d_out);
}

// Round 13
// 145.472 us; speedup vs baseline: 1.3913x; 1.3913x over previous
//
#include <hip/hip_runtime.h>
#include <math.h>

#define D_    100
#define DM_   200
#define DI_   400
#define G4_   1600
#define NN_   200
#define KP_   224   // padded K for MFMA (200 -> 224 = 7*32)

typedef __attribute__((ext_vector_type(8))) short bf16x8;
typedef __attribute__((ext_vector_type(4))) float f32x4;

__device__ __forceinline__ float sigf(float x){ return 1.0f/(1.0f+__expf(-x)); }
__device__ __forceinline__ unsigned short f2bf(float f){
    unsigned int b = __float_as_uint(f);
    b = (b + 0x7fffu + ((b>>16)&1u)) >> 16;
    return (unsigned short)b;
}
__device__ __forceinline__ float bf_lo(unsigned int w){ return __uint_as_float(w<<16); }
__device__ __forceinline__ float bf_hi(unsigned int w){ return __uint_as_float(w & 0xffff0000u); }

// ---------------------------------------------------------------------------
// warm1: stream float4 ranges into L2 with per-XCD coverage (r9 proven).
__global__ __launch_bounds__(256) void warm_kernel(
    const float4* __restrict__ p0, int n0, const float4* __restrict__ p1, int n1,
    const float4* __restrict__ p2, int n2, const float4* __restrict__ p3, int n3,
    const float4* __restrict__ p4, int n4, float* __restrict__ dump)
{
    int tid = threadIdx.x, bid = blockIdx.x;
    int total = n0 + n1 + n2 + n3 + n4;
    int nsl = gridDim.x >> 3;
    int slice = bid >> 3;
    int chunk = (total + nsl - 1) / nsl;
    int start = slice * chunk;
    int end = min(start + chunk, total);
    float acc = 0.f;
    for (int i = start + tid; i < end; i += 256){
        int j = i; const float4* p;
        if (j < n0) p = p0;
        else { j -= n0;
            if (j < n1) p = p1;
            else { j -= n1;
                if (j < n2) p = p2;
                else { j -= n2;
                    if (j < n3) p = p3;
                    else { j -= n3; p = p4; } } } }
        float4 v = p[j];
        acc += v.x + v.y + v.z + v.w;
    }
    #pragma unroll
    for (int o = 32; o; o >>= 1) acc += __shfl_down(acc, o);
    if ((tid & 63) == 0) dump[bid*4 + (tid >> 6)] = acc;
}

// ---------------------------------------------------------------------------
// prep: merged wtrans (blocks 0..349) + warm Whh[200:] (350..861) +
//       warm seW1/seW2 (862..1373).  256 thr.  (r12 proven)
__global__ __launch_bounds__(256) void prep_kernel(
    const float* __restrict__ Wih, const float* __restrict__ Whh,
    const float* __restrict__ seW1, const float* __restrict__ seW2,
    unsigned short* __restrict__ Bt0, unsigned short* __restrict__ Bt1,
    float* __restrict__ dump)
{
    int b = blockIdx.x, tid = threadIdx.x;
    if (b < 350){
        int m = b / 175; int bb = b - m*175;
        int kt = bb / 25, ct = bb % 25;
        const float* W = m ? Whh : Wih;
        unsigned short* Bt = m ? Bt1 : Bt0;
        int k0 = kt*32, c0 = ct*64;
        __shared__ float t[32][65];
        for (int idx = tid; idx < 2048; idx += 256){
            int kk = idx >> 6, c = idx & 63;
            int k = k0 + kk;
            t[kk][c] = (k < 200) ? W[(long)k*G4_ + c0 + c] : 0.f;
        }
        __syncthreads();
        for (int idx = tid; idx < 1024; idx += 256){
            int c = idx >> 4, p = idx & 15;
            unsigned int u0 = f2bf(t[p*2][c]);
            unsigned int u1 = f2bf(t[p*2+1][c]);
            *(unsigned int*)(Bt + (long)(c0+c)*KP_ + k0 + p*2) = u0 | (u1 << 16);
        }
        return;
    }
    const float4* p; int total; int sub;
    if (b < 862){ sub = b - 350; p = (const float4*)(Whh + 200*G4_); total = 80000; }
    else        { sub = b - 862; p = (const float4*)seW1;            total = 40000; }
    int nsl = 64, slice = sub >> 3;
    int chunk = (total + nsl - 1) / nsl;
    int start = slice * chunk;
    int end = min(start + chunk, total);
    float acc = 0.f;
    if (b < 862){
        for (int i = start + tid; i < end; i += 256){ float4 v = p[i]; acc += v.x+v.y+v.z+v.w; }
    } else {
        const float4* q1 = (const float4*)seW1;
        const float4* q2 = (const float4*)seW2;
        for (int i = start + tid; i < end; i += 256){
            float4 v = (i < 20000) ? q1[i] : q2[i-20000];
            acc += v.x+v.y+v.z+v.w;
        }
    }
    #pragma unroll
    for (int o = 32; o; o >>= 1) acc += __shfl_down(acc, o);
    if ((tid & 63) == 0) dump[b*4 + (tid >> 6)] = acc;
}

// ---------------------------------------------------------------------------
// Kernel 1: views v7 (proven).  grid = 1250, 128 thr, 8 rows/block.
__global__ __launch_bounds__(128) void views_kernel(
    const float* __restrict__ ent_emb, const float* __restrict__ rel_emb,
    const float* __restrict__ W1, const float* __restrict__ b1,
    const float* __restrict__ W2, const float* __restrict__ b2,
    const float* __restrict__ W3, const float* __restrict__ b3,
    const float* __restrict__ attW1, const float* __restrict__ attW2,
    unsigned short* __restrict__ ent_bf, float* __restrict__ rs_in, float* __restrict__ rs_out)
{
    int bid = blockIdx.x, tid = threadIdx.x;
    bool isRel = bid < 625;
    int row0 = (isRel ? bid : bid - 625) * 8;
    const float* src = isRel ? rel_emb : ent_emb;

    __shared__ float4 eT4[25][9];
    __shared__ float  ys[3][8][D_];
    __shared__ float  invn[3][8];
    __shared__ float  aws[2][D_];

    for (int idx = tid; idx < 200; idx += 128){
        int r = idx / 25, c4 = idx % 25;
        eT4[c4][r] = *(const float4*)(src + (long)(row0+r)*D_ + c4*4);
    }
    if (isRel){
        for (int idx = tid; idx < 200; idx += 128)
            aws[idx/100][idx%100] = (idx < 100) ? attW1[idx] : attW2[idx-100];
    }
    __syncthreads();

    if (tid < 75){
        int v = tid / 25, cq = tid % 25, c0 = cq*4;
        const float* Wv = (v==0) ? W1 : (v==1) ? W2 : W3;
        const float* bv = (v==0) ? b1 : (v==1) ? b2 : b3;
        float4 bb = *(const float4*)(bv + c0);
        float acc[8][4];
        #pragma unroll
        for (int r = 0; r < 8; ++r){
            acc[r][0]=bb.x; acc[r][1]=bb.y; acc[r][2]=bb.z; acc[r][3]=bb.w;
        }
        for (int k4 = 0; k4 < 25; ++k4){
            const float* Wk = Wv + (long)(k4*4)*D_ + c0;
            float4 w0 = *(const float4*)(Wk);
            float4 w1 = *(const float4*)(Wk + D_);
            float4 w2 = *(const float4*)(Wk + 2*D_);
            float4 w3 = *(const float4*)(Wk + 3*D_);
            #pragma unroll
            for (int r = 0; r < 8; ++r){
                float4 e = eT4[k4][r];
                acc[r][0] += e.x*w0.x + e.y*w1.x + e.z*w2.x + e.w*w3.x;
                acc[r][1] += e.x*w0.y + e.y*w1.y + e.z*w2.y + e.w*w3.y;
                acc[r][2] += e.x*w0.z + e.y*w1.z + e.z*w2.z + e.w*w3.z;
                acc[r][3] += e.x*w0.w + e.y*w1.w + e.z*w2.w + e.w*w3.w;
            }
        }
        #pragma unroll
        for (int r = 0; r < 8; ++r)
            *(float4*)(&ys[v][r][c0]) = make_float4(acc[r][0], acc[r][1], acc[r][2], acc[r][3]);
    }
    __syncthreads();

    if (tid < 24){
        int v = tid / 8, r = tid % 8;
        float s = 0.f;
        #pragma unroll 4
        for (int j = 0; j < D_; ++j){ float t = ys[v][r][j]; s += t*t; }
        invn[v][r] = 1.f / fmaxf(sqrtf(s), 1e-12f);
    }
    __syncthreads();

    if (isRel){
        if (tid < 48){
            int which = tid & 1, p = tid >> 1;
            int v = p / 8, r = p % 8;
            float s = 0.f;
            #pragma unroll 4
            for (int j = 0; j < D_; ++j) s += ys[v][r][j]*aws[which][j];
            (which ? rs_out : rs_in)[(row0+r)*3+v] = s * invn[v][r];
        }
    } else {
        for (int idx = tid; idx < 600; idx += 128){
            int v = idx / 200, rq = idx - v*200;
            int r = rq / 25, c0 = (rq % 25)*4;
            float inv = invn[v][r];
            float4 y4 = *(const float4*)(&ys[v][r][c0]);
            ushort4 o;
            o.x = f2bf(y4.x*inv); o.y = f2bf(y4.y*inv);
            o.z = f2bf(y4.z*inv); o.w = f2bf(y4.w*inv);
            *(ushort4*)(ent_bf + ((long)(row0+r)*3+v)*D_ + c0) = o;
        }
    }
}

// ---------------------------------------------------------------------------
// Kernel 2: neigh (proven tree-softmax).  grid = (518, 3), 512 thr.
__global__ __launch_bounds__(512) void neigh_kernel(
    const int* __restrict__ qlc_out, const int* __restrict__ qlc_in,
    const int* __restrict__ qrc_out, const int* __restrict__ qrc_in,
    const int* __restrict__ slc_out, const int* __restrict__ slc_in,
    const int* __restrict__ src_out, const int* __restrict__ src_in,
    const unsigned short* __restrict__ ent_bf, const float* __restrict__ rs_in,
    const float* __restrict__ rs_out,
    float* __restrict__ X)
{
    int u = blockIdx.x, v = blockIdx.y, tid = threadIdx.x;
    const int *cin, *cout; int row, colOff;
    if      (u < 256){ int n=u;     cout=qlc_out+n*NN_*2; cin=qlc_in+n*NN_*2; row=v*256+n;   colOff=0;   }
    else if (u < 512){ int n=u-256; cout=qrc_out+n*NN_*2; cin=qrc_in+n*NN_*2; row=v*256+n;   colOff=100; }
    else if (u < 515){ int f=u-512; cout=slc_out+f*NN_*2; cin=slc_in+f*NN_*2; row=768+f*3+v; colOff=0;   }
    else             { int f=u-515; cout=src_out+f*NN_*2; cin=src_in+f*NN_*2; row=768+f*3+v; colOff=100; }

    __shared__ int   ioff[NN_], ooff[NN_];
    __shared__ float ain[NN_], aout[NN_];
    __shared__ float sv[2][NN_];
    __shared__ float red[512];
    __shared__ float pin[4][D_], pout[4][D_];

    if (tid < NN_){
        int rrel = cin[tid*2], rent = cin[tid*2+1];
        ioff[tid] = (rent*3+v)*D_;
        sv[0][tid] = rs_in[rrel*3+v];
    } else if (tid >= 256 && tid < 256+NN_){
        int k = tid - 256;
        int rrel = cout[k*2], rent = cout[k*2+1];
        ooff[k] = (rent*3+v)*D_;
        sv[1][k] = rs_out[rrel*3+v];
    }
    __syncthreads();

    int half = tid >> 8, l = tid & 255, base = half << 8;
    float x = (l < NN_) ? sv[half][l] : -1e30f;
    red[tid] = x; __syncthreads();
    for (int s = 128; s > 0; s >>= 1){
        if (l < s) red[base+l] = fmaxf(red[base+l], red[base+l+s]);
        __syncthreads();
    }
    float m = red[base]; __syncthreads();
    float e = (l < NN_) ? __expf(x - m) : 0.f;
    red[tid] = e; __syncthreads();
    for (int s = 128; s > 0; s >>= 1){
        if (l < s) red[base+l] += red[base+l+s];
        __syncthreads();
    }
    float S = red[base];
    if (l < NN_){ if (half) aout[l] = e/S; else ain[l] = e/S; }
    __syncthreads();

    int g = tid >> 6, ln = tid & 63;
    if (ln < 50){
        int d0 = ln*2;
        bool isOut = g >= 4;
        int k0 = (g & 3) * 50;
        const int*   offA = isOut ? ooff : ioff;
        const float* aA   = isOut ? aout : ain;
        float acc0 = 0.f, acc1 = 0.f;
        #pragma unroll 5
        for (int kk = 0; kk < 50; ++kk){
            int k = k0 + kk;
            unsigned int w = *(const unsigned int*)(ent_bf + offA[k] + d0);
            float a = aA[k];
            acc0 += a * bf_lo(w);
            acc1 += a * bf_hi(w);
        }
        float2* p = isOut ? (float2*)&pout[g&3][d0] : (float2*)&pin[g&3][d0];
        *p = make_float2(acc0, acc1);
    }
    __syncthreads();

    if (tid < D_){
        float hi = pin[0][tid]+pin[1][tid]+pin[2][tid]+pin[3][tid];
        float ho = pout[0][tid]+pout[1][tid]+pout[2][tid]+pout[3][tid];
        float ea = __expf(hi), ec = __expf(ho);
        X[(long)row*DM_ + colOff + tid] = tanhf((hi*ea + ho*ec)/(ea+ec));
    }
}

// ---------------------------------------------------------------------------
// Kernel 3: senc v8 fused + Abf bf16 store (r12 proven). grid = 389, 512 thr.
__global__ __launch_bounds__(512) void senc_kernel(
    const float* __restrict__ X,
    const float* __restrict__ seW1, const float* __restrict__ seb1,
    const float* __restrict__ seW2, const float* __restrict__ seb2,
    const float* __restrict__ ln_g, const float* __restrict__ ln_b,
    float* __restrict__ qg, float* __restrict__ sEnc,
    unsigned short* __restrict__ Abf)
{
    int b = blockIdx.x, tid = threadIdx.x;
    int r0 = b*2;

    __shared__ float xT[DM_][2];
    __shared__ float tT[DI_][2];
    __shared__ float pc[2][DM_][2];
    __shared__ float hv[2][DM_];
    __shared__ float part[2][4][2];

    for (int idx = tid; idx < 400; idx += 512){
        int r = idx / DM_, k = idx - r*DM_;
        int row = r0 + r;
        xT[k][r] = (row < 777) ? X[(long)row*DM_ + k] : 0.f;
    }
    __syncthreads();

    if (tid < DI_){
        int col = tid;
        float a0, a1; a0 = a1 = seb1[col];
        #pragma unroll 4
        for (int k = 0; k < DM_; ++k){
            float w = seW1[(long)k*DI_ + col];
            float2 e = *(const float2*)(&xT[k][0]);
            a0 += e.x*w; a1 += e.y*w;
        }
        tT[col][0] = fmaxf(a0, 0.f);
        tT[col][1] = fmaxf(a1, 0.f);
    }
    __syncthreads();

    if (tid < 400){
        int col = tid % DM_, kh = tid / DM_;
        float a0 = 0.f, a1 = 0.f;
        #pragma unroll 4
        for (int kk = 0; kk < 200; ++kk){
            int k = kh*200 + kk;
            float w = seW2[(long)k*DM_ + col];
            float2 t = *(const float2*)(&tT[k][0]);
            a0 += t.x*w; a1 += t.y*w;
        }
        pc[kh][col][0] = a0; pc[kh][col][1] = a1;
    }
    __syncthreads();

    if (tid < DM_){
        int col = tid;
        float bb = seb2[col];
        hv[0][col] = pc[0][col][0] + pc[1][col][0] + bb + xT[col][0];
        hv[1][col] = pc[0][col][1] + pc[1][col][1] + bb + xT[col][1];
    }
    __syncthreads();

    {
        int row = tid >> 8, l = tid & 255, w = l >> 6, lane = l & 63;
        float v = (l < DM_) ? hv[row][l] : 0.f;
        float s1 = v, s2 = v*v;
        #pragma unroll
        for (int o = 32; o; o >>= 1){ s1 += __shfl_down(s1, o); s2 += __shfl_down(s2, o); }
        if (lane == 0){ part[row][w][0] = s1; part[row][w][1] = s2; }
    }
    __syncthreads();

    if (tid < 400){
        int row = tid / DM_, col = tid % DM_;
        int grow = r0 + row;
        if (grow < 777){
            float s1 = part[row][0][0]+part[row][1][0]+part[row][2][0]+part[row][3][0];
            float s2 = part[row][0][1]+part[row][1][1]+part[row][2][1]+part[row][3][1];
            float mu = s1 * (1.f/DM_);
            float rs = rsqrtf(s2 * (1.f/DM_) - mu*mu + 1e-5f);
            float val = ln_g[col]*(hv[row][col]-mu)*rs + ln_b[col];
            if (grow < 768){
                qg[(long)grow*DM_ + col] = val;
                Abf[(long)grow*KP_ + col] = f2bf(val);
            } else {
                sEnc[(long)(grow-768)*DM_ + col] = val;
            }
        }
    } else if (tid < 448){
        int t = tid - 400;
        int rr = t / 24, cc = t % 24;
        int grow = r0 + rr;
        if (grow < 768) Abf[(long)grow*KP_ + 200 + cc] = 0;
    }
}

// ---------------------------------------------------------------------------
// Kernel 4: sw (+ sg).  grid = 75, 64 thr.
__global__ __launch_bounds__(64) void sw_kernel(
    const float* __restrict__ sEnc, const float* __restrict__ Whh,
    float* __restrict__ sg, float* __restrict__ sW)
{
    int b = blockIdx.x, tid = threadIdx.x;
    int s = b / 25, c0 = (b - s*25)*64;
    __shared__ float sgl[DM_];
    for (int j = tid; j < DM_; j += 64){
        float val = (sEnc[s*DM_ + j] + sEnc[(3+s)*DM_ + j] + sEnc[(6+s)*DM_ + j]) * (1.f/3.f);
        sgl[j] = val;
        if (c0 == 0) sg[s*DM_ + j] = val;
    }
    __syncthreads();
    int col = c0 + tid;
    float acc = 0.f;
    #pragma unroll 4
    for (int i = 0; i < DM_; ++i) acc += sgl[i] * Whh[(long)(DM_+i)*G4_ + col];
    sW[s*G4_ + col] = acc;
}

// ---------------------------------------------------------------------------
// gemm_mfma (r11 proven): C[768x1600] = Abf @ Bt^T + fp32 epilogue.
// grid = 1200 blocks, 256 thr = 4 waves; wave = one 16x16 tile.
__global__ __launch_bounds__(256) void gemm_mfma_kernel(
    const unsigned short* __restrict__ Abf, const unsigned short* __restrict__ Bt,
    const float* __restrict__ qW0, const float* __restrict__ sW,
    const float* __restrict__ alpha,
    const float* __restrict__ bih, const float* __restrict__ bhh,
    float* __restrict__ C, int mode)
{
    int bx = blockIdx.x % 25, by = blockIdx.x / 25;
    int tid = threadIdx.x;
    int w = tid >> 6, lane = tid & 63;
    int row0 = by*16;
    int col0 = bx*64 + w*16;
    int kg = (lane >> 4) * 8;

    const unsigned short* Ap = Abf + (long)(row0 + (lane & 15))*KP_ + kg;
    const unsigned short* Bp = Bt  + (long)(col0 + (lane & 15))*KP_ + kg;

    f32x4 acc = {0.f, 0.f, 0.f, 0.f};
    #pragma unroll
    for (int kt = 0; kt < 7; ++kt){
        bf16x8 a = *(const bf16x8*)(Ap + kt*32);
        bf16x8 b = *(const bf16x8*)(Bp + kt*32);
        acc = __builtin_amdgcn_mfma_f32_16x16x32_bf16(a, b, acc, 0, 0, 0);
    }

    int crow0 = row0 + (lane >> 4)*4;
    int ccol  = col0 + (lane & 15);
    if (mode == 0){
        float add = bih[ccol] + bhh[ccol];
        #pragma unroll
        for (int i = 0; i < 4; ++i)
            C[(long)(crow0+i)*G4_ + ccol] = acc[i] + add;
    } else {
        float s0 = sW[ccol], s1 = sW[G4_ + ccol], s2 = sW[2*G4_ + ccol];
        #pragma unroll
        for (int i = 0; i < 4; ++i){
            int row = crow0 + i;
            float a0 = alpha[row*3+0], a1 = alpha[row*3+1], a2 = alpha[row*3+2];
            C[(long)row*G4_ + ccol] = acc[i] + qW0[(long)row*G4_ + ccol]
                                    + a0*s0 + a1*s1 + a2*s2;
        }
    }
}

// ---------------------------------------------------------------------------
// LSTM cell + support attention (r11 proven) + fused h->bf16 store (no fp32 h).
// grid 192 x 256 thr, 4 rows/block.
__global__ __launch_bounds__(256) void cell_kernel(
    const float* __restrict__ G, const float* __restrict__ qg,
    const float* __restrict__ sg, float* __restrict__ c,
    unsigned short* __restrict__ hbf,
    float* __restrict__ alpha, float* __restrict__ sAll,
    int first, int last)
{
    int b = blockIdx.x, tid = threadIdx.x;
    int row0 = b*4;
    __shared__ float hbuf[4][DM_];
    __shared__ float sup[600];
    __shared__ float lg[4][3];

    for (int i = tid; i < 600; i += 256) sup[i] = sg[i];

    for (int idx = tid; idx < 4*DI_; idx += 256){
        int r = idx / DI_, j = idx - r*DI_;
        int row = row0 + r;
        const float* g = G + (long)row*G4_;
        float gi = g[j], gf = g[DI_+j], gg = g[2*DI_+j];
        float cold = first ? 0.f : c[(long)row*DI_ + j];
        float c2 = sigf(gf)*cold + sigf(gi)*tanhf(gg);
        c[(long)row*DI_ + j] = c2;
        if (j < DM_){
            float go = g[3*DI_+j];
            float hval = qg[(long)row*DM_ + j] + sigf(go)*tanhf(c2);
            hbuf[r][j] = hval;
            hbf[(long)row*KP_ + j] = f2bf(hval);
        }
    }
    __syncthreads();

    if (!last){
        if (tid < 192){
            int p = tid >> 4, l = tid & 15, r = p/3, s = p - r*3;
            float part = 0.f;
            for (int d = l; d < DM_; d += 16) part += hbuf[r][d]*sup[s*DM_+d];
            for (int o = 8; o; o >>= 1) part += __shfl_down(part, o, 16);
            if (!l) lg[r][s] = part;
        }
        __syncthreads();
        if (tid < 4){
            float l0 = lg[tid][0], l1 = lg[tid][1], l2 = lg[tid][2];
            float m = fmaxf(l0, fmaxf(l1, l2));
            float e0 = __expf(l0-m), e1 = __expf(l1-m), e2 = __expf(l2-m);
            float inv = 1.f/(e0+e1+e2);
            alpha[(row0+tid)*3+0] = e0*inv;
            alpha[(row0+tid)*3+1] = e1*inv;
            alpha[(row0+tid)*3+2] = e2*inv;
        }
    } else {
        int v = row0 >> 8;
        if (tid < 64){
            int r = tid >> 4, l = tid & 15;
            float part = 0.f;
            for (int d = l; d < DM_; d += 16) part += hbuf[r][d]*sup[v*DM_+d];
            for (int o = 8; o; o >>= 1) part += __shfl_down(part, o, 16);
            if (!l) sAll[row0+r] = part;
        }
    }
}

// ---------------------------------------------------------------------------
__global__ void final_kernel(const float* __restrict__ sAll, float* __restrict__ out){
    int n = blockIdx.x*blockDim.x + threadIdx.x;
    if (n < 256) out[n] = fmaxf(sAll[n], fmaxf(sAll[256+n], sAll[512+n]));
}

// ---------------------------------------------------------------------------
extern "C" void kernel_launch(void* const* d_in, const int* in_sizes, int n_in,
                              void* d_out, int out_size, void* d_ws, size_t ws_size,
                              hipStream_t stream)
{
    const float* ent_emb=(const float*)d_in[0];
    const float* rel_emb=(const float*)d_in[1];
    const float* W1=(const float*)d_in[2];  const float* b1=(const float*)d_in[3];
    const float* W2=(const float*)d_in[4];  const float* b2=(const float*)d_in[5];
    const float* W3=(const float*)d_in[6];  const float* b3=(const float*)d_in[7];
    const float* attW1=(const float*)d_in[8];
    const float* attW2=(const float*)d_in[10];
    const float* seW1=(const float*)d_in[12]; const float* seb1=(const float*)d_in[13];
    const float* seW2=(const float*)d_in[14]; const float* seb2=(const float*)d_in[15];
    const float* ln_g=(const float*)d_in[16]; const float* ln_b=(const float*)d_in[17];
    const float* Wih=(const float*)d_in[18];  const float* bih=(const float*)d_in[19];
    const float* Whh=(const float*)d_in[20];  const float* bhh=(const float*)d_in[21];
    const int* qlc_out=(const int*)d_in[24];  const int* qlc_in=(const int*)d_in[25];
    const int* qrc_out=(const int*)d_in[27];  const int* qrc_in=(const int*)d_in[28];
    const int* slc_out=(const int*)d_in[30];  const int* slc_in=(const int*)d_in[31];
    const int* src_out=(const int*)d_in[33];  const int* src_in=(const int*)d_in[34];

    float* ws = (float*)d_ws;
    unsigned short* ent_bf = (unsigned short*)ws;  // 1.5M bf16 (750k float slots)
    float* gates = ws;                 // overlays ent_bf (disjoint lifetime)
    float* rs_in = ws + 1500000;       // 15,000
    float* rs_out= ws + 1515000;       // 15,000
    float* X     = ws + 1530000;       // 156,800 (784x200; neigh -> senc)
    float* qg    = ws + 1686800;       // 153,600
    float* sEnc  = ws + 1840400;       // 1,800
    float* sg    = ws + 1842200;       // 600
    float* qW0   = ws + 1842800;       // 1,228,800
    float* cst   = ws + 3071600;       // 307,200
    float* alpha = ws + 3378800;       // 2,304
    float* sW    = ws + 3381104;       // 4,800
    float* sAll  = ws + 3385904;       // 768
    float* dump  = ws + 3386672;       // 8,192 (warm sink)
    unsigned short* Abf = (unsigned short*)(ws + 3394864);  // 768x224 bf16
    unsigned short* Bt0 = (unsigned short*)(ws + 3480880);  // 1600x224 bf16
    unsigned short* Bt1 = (unsigned short*)(ws + 3660080);  // 1600x224 bf16

    // warm1: embeddings actually used (ent rows 0..4999, all rel) + W1-3
    warm_kernel<<<2048, 256, 0, stream>>>(
        (const float4*)ent_emb, 125000, (const float4*)rel_emb, 125000,
        (const float4*)W1, 2500, (const float4*)W2, 2500,
        (const float4*)W3, 2500, dump);
    views_kernel<<<1250, 128, 0, stream>>>(ent_emb, rel_emb, W1,b1,W2,b2,W3,b3,
                                           attW1, attW2, ent_bf, rs_in, rs_out);
    neigh_kernel<<<dim3(518,3), 512, 0, stream>>>(qlc_out,qlc_in,qrc_out,qrc_in,
                                                  slc_out,slc_in,src_out,src_in,
                                                  ent_bf, rs_in, rs_out, X);
    // prep: wtrans (Bt0/Bt1) + warm Whh[200:] + warm seW1/seW2
    prep_kernel<<<1374, 256, 0, stream>>>(Wih, Whh, seW1, seW2, Bt0, Bt1, dump);
    senc_kernel<<<389, 512, 0, stream>>>(X, seW1, seb1, seW2, seb2,
                                         ln_g, ln_b, qg, sEnc, Abf);
    sw_kernel<<<75, 64, 0, stream>>>(sEnc, Whh, sg, sW);

    // qW0 = qg @ Wih + bih + bhh   (MFMA)
    gemm_mfma_kernel<<<1200, 256, 0, stream>>>(Abf, Bt0, nullptr, nullptr, nullptr,
                                               bih, bhh, qW0, 0);
    cell_kernel<<<192, 256, 0, stream>>>(qW0, qg, sg, cst, Abf, alpha, sAll, 1, 0);
    for (int s = 1; s < 4; ++s){
        gemm_mfma_kernel<<<1200, 256, 0, stream>>>(Abf, Bt1, qW0, sW, alpha,
                                                   nullptr, nullptr, gates, 1);
        cell_kernel<<<192, 256, 0, stream>>>(gates, qg, sg, cst, Abf, alpha, sAll,
                                             0, (s==3) ? 1 : 0);
    }
    final_kernel<<<1, 256, 0, stream>>>(sAll, (float*)d_out);
}